// Round 8
// baseline (187.399 us; speedup 1.0000x reference)
//
#include <hip/hip_runtime.h>
#include <hip/hip_fp16.h>
#include <cmath>

// Problem constants: (N,C,H,W) = (16,3,512,512), fp32
#define PLANE (512*512)          // 262144
#define NPLANES 48               // N*C
#define NEL (48*PLANE)           // 12582912

struct Taps { float k[9]; };
struct CMat { float w[3][3]; };   // C-axis 9-tap blur collapsed to 3x3 matrix

// ws: fp16 HW-blurred logs, TILED:
//   half index(p, h, w) = ((h*8 + (w>>6))*96 + p)*64 + (w&63)
//   p in [0,48) = image E planes, [48,96) = image G planes.  48 MB total.

// ---------------------------------------------------------------------------
// Kernel 1: fused log + W-blur + H-blur.
//  - Each WAVE: one full-width (512-col) 16-row output strip of one plane.
//    8 cols/lane -> W-halo entirely via shuffles + register mirror at lanes
//    0/63 (no halo loads, no wasted halo logs - R7 spent 4/row on all lanes).
//  - 4 waves per 256-thread block (4 consecutive planes, same strip): R4-R7
//    used single-wave workgroups and occupancy pinned at ~8 waves/CU
//    regardless of grid size -> workgroup-slot cap, not VGPRs. 768 blocks
//    = 3 blocks/CU = 12 waves/CU guaranteed resident.
//  - 16-row strips: halo amp 1.5x fetch (R5's 8-row/2.0x regressed).
//  - 9-row ring, fully unrolled 24-iteration loop (compile-time slots),
//    depth-3 named-register load pipeline.
// grid (32 rowgroups, 24 plane-quads), block 256.
// ---------------------------------------------------------------------------
__global__ __launch_bounds__(256)
void k_blur_hw(const float* __restrict__ inE, const float* __restrict__ inG,
               ushort* __restrict__ ws, Taps tp)
{
    const int l  = threadIdx.x & 63;          // lane, owns cols 8l..8l+7
    const int r0 = blockIdx.x * 16;           // first output row of strip
    const int z  = blockIdx.y * 4 + (threadIdx.x >> 6);   // plane 0..95

    const float* src = (z < NPLANES) ? (inE + z * PLANE)
                                     : (inG + (z - NPLANES) * PLANE);

    const bool is0  = (l == 0);
    const bool is63 = (l == 63);
    // lane's slot in the tiled ws: tile = l>>3, inner = (l&7)*8
    const int  vout = (l >> 3) * 6144 + (l & 7) * 8;

    float ring[9][8];                         // W-blurred rows, slot = j % 9

#define FOLD(r) ((r) < 0 ? (-1 - (r)) : ((r) > 511 ? (1023 - (r)) : (r)))

    // preload input rows j=0,1,2 (plane rows r0-4..r0-2, folded)
    float4 a, b, c, d, e, f;
    {
        const float* rp;
        rp = src + FOLD(r0 - 4) * 512 + l * 8;
        a = *(const float4*)rp;  b = *(const float4*)(rp + 4);
        rp = src + FOLD(r0 - 3) * 512 + l * 8;
        c = *(const float4*)rp;  d = *(const float4*)(rp + 4);
        rp = src + FOLD(r0 - 2) * 512 + l * 8;
        e = *(const float4*)rp;  f = *(const float4*)(rp + 4);
    }

#pragma unroll
    for (int j = 0; j < 24; ++j) {            // input rows r0-4 .. r0+19
        // log of current row (regs a,b) -- 8 logs, all useful
        float win[16];
        win[4]  = __logf(a.x + 1e-6f);
        win[5]  = __logf(a.y + 1e-6f);
        win[6]  = __logf(a.z + 1e-6f);
        win[7]  = __logf(a.w + 1e-6f);
        win[8]  = __logf(b.x + 1e-6f);
        win[9]  = __logf(b.y + 1e-6f);
        win[10] = __logf(b.z + 1e-6f);
        win[11] = __logf(b.w + 1e-6f);

        // rotate load pipeline; issue row j+3 (3 rows in flight)
        a = c; b = d; c = e; d = f;
        if (j + 3 < 24) {
            const float* nrp = src + FOLD(r0 - 1 + j) * 512 + l * 8;
            e = *(const float4*)nrp;
            f = *(const float4*)(nrp + 4);
        }

        // W-halo via shuffles; image-edge mirror = reverse of own values
        float s;
        s = __shfl_up(win[8], 1);   win[0]  = is0  ? win[7]  : s;
        s = __shfl_up(win[9], 1);   win[1]  = is0  ? win[6]  : s;
        s = __shfl_up(win[10], 1);  win[2]  = is0  ? win[5]  : s;
        s = __shfl_up(win[11], 1);  win[3]  = is0  ? win[4]  : s;
        s = __shfl_down(win[4], 1); win[12] = is63 ? win[11] : s;
        s = __shfl_down(win[5], 1); win[13] = is63 ? win[10] : s;
        s = __shfl_down(win[6], 1); win[14] = is63 ? win[9]  : s;
        s = __shfl_down(win[7], 1); win[15] = is63 ? win[8]  : s;

        // W-blur -> ring slot j%9 (compile-time via full unroll)
#pragma unroll
        for (int i = 0; i < 8; ++i) {
            float o = 0.f;
#pragma unroll
            for (int t = 0; t < 9; ++t) o += tp.k[t] * win[i + t];
            ring[j % 9][i] = o;
        }

        // H-blur + fp16 store once 9 rows live (output plane row r0+j-8)
        if (j >= 8) {
            float acc[8];
#pragma unroll
            for (int i = 0; i < 8; ++i) {
                float o = 0.f;
#pragma unroll
                for (int t = 0; t < 9; ++t)
                    o += tp.k[t] * ring[(j - 8 + t) % 9][i];
                acc[i] = o;
            }
            const int ro = r0 + j - 8;
            __half2 p0, p1, p2, p3;
            p0.x = __float2half(acc[0]); p0.y = __float2half(acc[1]);
            p1.x = __float2half(acc[2]); p1.y = __float2half(acc[3]);
            p2.x = __float2half(acc[4]); p2.y = __float2half(acc[5]);
            p3.x = __float2half(acc[6]); p3.y = __float2half(acc[7]);
            ushort* dp = ws + ((ro * 8 + (l >> 3)) * 96 + z) * 64 + (l & 7) * 8;
            *(uint4*)dp = make_uint4(*(uint*)&p0, *(uint*)&p1,
                                     *(uint*)&p2, *(uint*)&p3);
        }
    }
#undef FOLD
}

// ---------------------------------------------------------------------------
// Kernel 2: C-blur + N-blur + loss, register-light (9-slot ring, 3x3 C-matrix),
// software-pipelined loads; fp16 ws reads; per-block atomicAdd to out.
// grid (1024), block (256); one thread per (h,w).
// ---------------------------------------------------------------------------
__global__ __launch_bounds__(256)
void k_cn_loss(const __half* __restrict__ ws, const float* __restrict__ Ie,
               const float* __restrict__ Ig, float* __restrict__ out,
               Taps tp, CMat cm)
{
    const int tid = threadIdx.x;
    const int hw  = blockIdx.x * 256 + tid;
    const __half* wbase = ws + (hw >> 6) * (96 * 64) + (hw & 63);
    // E plane q at wbase[q*64], G plane q at wbase[(48+q)*64]

    float re[9][3];   // ring of C-blurred smoothed-log(E), slot = m % 9
    float rg[9][3];

#define LOADRAW(m, vE, vG)                                                     \
    vE[0] = __half2float(wbase[((m) * 3 + 0) * 64]);                           \
    vE[1] = __half2float(wbase[((m) * 3 + 1) * 64]);                           \
    vE[2] = __half2float(wbase[((m) * 3 + 2) * 64]);                           \
    vG[0] = __half2float(wbase[(48 + (m) * 3 + 0) * 64]);                      \
    vG[1] = __half2float(wbase[(48 + (m) * 3 + 1) * 64]);                      \
    vG[2] = __half2float(wbase[(48 + (m) * 3 + 2) * 64]);

#define CBLUR(v, dst)                                                          \
    dst[0] = cm.w[0][0] * v[0] + cm.w[0][1] * v[1] + cm.w[0][2] * v[2];        \
    dst[1] = cm.w[1][0] * v[0] + cm.w[1][1] * v[1] + cm.w[1][2] * v[2];        \
    dst[2] = cm.w[2][0] * v[0] + cm.w[2][1] * v[1] + cm.w[2][2] * v[2];

#pragma unroll
    for (int m = 0; m < 4; ++m) {
        float vE[3], vG[3];
        LOADRAW(m, vE, vG);
        CBLUR(vE, re[m]); CBLUR(vG, rg[m]);
    }
    float nvE[3], nvG[3];
    LOADRAW(4, nvE, nvG);
    float ieq[3], igq[3];
#pragma unroll
    for (int c = 0; c < 3; ++c) {
        ieq[c] = Ie[c * PLANE + hw] + 1e-6f;
        igq[c] = Ig[c * PLANE + hw] + 1e-6f;
    }

    float acc = 0.f;
#pragma unroll
    for (int n = 0; n < 16; ++n) {
        float nie[3], nig[3];
        if (n + 1 < 16) {
#pragma unroll
            for (int c = 0; c < 3; ++c) {
                nie[c] = Ie[((n + 1) * 3 + c) * PLANE + hw] + 1e-6f;
                nig[c] = Ig[((n + 1) * 3 + c) * PLANE + hw] + 1e-6f;
            }
        }
        const int mnew = n + 4;
        if (mnew < 16) {
            CBLUR(nvE, re[mnew % 9]); CBLUR(nvG, rg[mnew % 9]);
            if (mnew + 1 < 16) { LOADRAW(mnew + 1, nvE, nvG); }
        }
#pragma unroll
        for (int c = 0; c < 3; ++c) {
            float se = 0.f, sg = 0.f;
#pragma unroll
            for (int t = 0; t < 9; ++t) {
                int m = n - 4 + t;
                m = (m < 0) ? (-1 - m) : ((m > 15) ? (31 - m) : m);  // compile-time
                se += tp.k[t] * re[m % 9][c];
                sg += tp.k[t] * rg[m % 9][c];
            }
            float ee = __expf(-se);                  // 1/Le
            float eg = __expf(-sg);
            float Re = ieq[c] * ee;
            float Rg = igq[c] * eg;
            float Le = __builtin_amdgcn_rcpf(ee);    // exp(se)
            float Lg = __builtin_amdgcn_rcpf(eg);
            float dr = Re - Rg;
            float dl = Le - Lg;
            acc += dr * dr + dl * dl;
        }
        if (n + 1 < 16) {
#pragma unroll
            for (int c = 0; c < 3; ++c) { ieq[c] = nie[c]; igq[c] = nig[c]; }
        }
    }
#undef LOADRAW
#undef CBLUR

    __shared__ float red[256];
    red[tid] = acc;
    __syncthreads();
#pragma unroll
    for (int s = 128; s > 0; s >>= 1) {
        if (tid < s) red[tid] += red[tid + s];
        __syncthreads();
    }
    if (tid == 0) atomicAdd(out, red[0] * (1.0f / (float)NEL));
}

extern "C" void kernel_launch(void* const* d_in, const int* in_sizes, int n_in,
                              void* d_out, int out_size, void* d_ws, size_t ws_size,
                              hipStream_t stream) {
    const float* Ie = (const float*)d_in[0];
    const float* Ig = (const float*)d_in[1];

    // Gaussian taps: sigma=1, radius=int(4*1+0.5)=4, double-precision normalize
    Taps tp;
    {
        double kk[9], s = 0.0;
        for (int i = 0; i < 9; ++i) { double x = (double)(i - 4); kk[i] = exp(-0.5 * x * x); s += kk[i]; }
        for (int i = 0; i < 9; ++i) tp.k[i] = (float)(kk[i] / s);
    }

    // C-axis (size 3) 9-tap symmetric blur collapsed to a 3x3 matrix
    CMat cm;
    {
        for (int c = 0; c < 3; ++c) {
            cm.w[c][0] = cm.w[c][1] = cm.w[c][2] = 0.f;
            for (int t = 0; t < 9; ++t) {
                int m = c - 4 + t;
                int mm = ((m % 6) + 6) % 6;          // symmetric reflect, period 6
                if (mm > 2) mm = 5 - mm;
                cm.w[c][mm] += tp.k[t];
            }
        }
    }

    ushort* ws = (ushort*)d_ws;          // tiled fp16 blurred logs, 48 MB

    hipMemsetAsync(d_out, 0, sizeof(float), stream);  // zero the atomic target
    dim3 g1(32, 24);
    k_blur_hw<<<g1, 256, 0, stream>>>(Ie, Ig, ws, tp);
    k_cn_loss<<<1024, 256, 0, stream>>>((const __half*)ws, Ie, Ig,
                                        (float*)d_out, tp, cm);
}

// Round 9
// 173.054 us; speedup vs baseline: 1.0829x; 1.0829x over previous
//
#include <hip/hip_runtime.h>
#include <hip/hip_fp16.h>
#include <cmath>

// Problem constants: (N,C,H,W) = (16,3,512,512), fp32
#define PLANE (512*512)          // 262144
#define NPLANES 48               // N*C
#define NEL (48*PLANE)           // 12582912

struct Taps { float k[9]; };
struct CMat { float w[3][3]; };   // C-axis 9-tap blur collapsed to 3x3 matrix

// ws: fp16 HW-blurred logs, TILED:
//   half index(p, h, w) = ((h*8 + (w>>6))*96 + p)*64 + (w&63)
//   p in [0,48) = image E planes, [48,96) = image G planes.  48 MB total.

// ---------------------------------------------------------------------------
// Kernel 1 (R7-exact, best measured 63.3us): fused log + W-blur + H-blur.
// One WAVE per (32-row strip x 256-col half). 4 cols/lane. W-halo: lanes
// 1..62 via shuffle; lanes 0/63 via one predicated float4 load (or register
// mirror at the image edge). 10-row ring. grid (32, 96), block 64.
// ---------------------------------------------------------------------------
__global__ __launch_bounds__(64)
void k_blur_hw(const float* __restrict__ inE, const float* __restrict__ inG,
               ushort* __restrict__ ws, Taps tp)
{
    const int l    = threadIdx.x;
    const int w0   = (blockIdx.x & 1) * 256;     // W half
    const int r0   = (blockIdx.x >> 1) * 32;     // 16 rowgroups
    const int z    = blockIdx.y;                 // plane 0..95

    const float* src = (z < NPLANES) ? (inE + z * PLANE)
                                     : (inG + (z - NPLANES) * PLANE);

    const int  col   = w0 + 4 * l;               // first of this lane's 4 cols
    const bool is0   = (l == 0);
    const bool is63  = (l == 63);
    const bool ledge = (w0 == 0);
    const bool redge = (w0 + 256 == 512);
    const bool do_halo = (is0 && !ledge) || (is63 && !redge);
    const int  hoff  = is0 ? (w0 - 4) : (w0 + 256);  // halo float4 col
    const int  tile  = col >> 6;                 // w-tile 0..7
    const int  inner = col & 63;

    float ring[10][4];                           // W-blurred rows, slot = j % 10

#define FOLD(r) ((r) < 0 ? (-1 - (r)) : ((r) > 511 ? (1023 - (r)) : (r)))

    // preload rows j=0,1,2 (plane rows r0-4..r0-2)
    float4 pown[3], phal[3];
    phal[0] = phal[1] = phal[2] = make_float4(1.f, 1.f, 1.f, 1.f);
#pragma unroll
    for (int s = 0; s < 3; ++s) {
        const float* rp = src + FOLD(r0 - 4 + s) * 512;
        pown[s] = *(const float4*)(rp + col);
        if (do_halo) phal[s] = *(const float4*)(rp + hoff);
    }

    for (int jb = 0; jb < 40; jb += 10) {
#pragma unroll
        for (int u = 0; u < 10; ++u) {
            const int j = jb + u;                // input row 0..39 (plane r0-4+j)

            float4 own = pown[0], hal = phal[0];
            pown[0] = pown[1]; pown[1] = pown[2];
            phal[0] = phal[1]; phal[1] = phal[2];
            if (j + 3 < 40) {                    // load row j+3 (depth-3 pipe)
                const float* rp = src + FOLD(r0 - 1 + j) * 512;
                pown[2] = *(const float4*)(rp + col);
                if (do_halo) phal[2] = *(const float4*)(rp + hoff);
            }

            const float w4 = __logf(own.x + 1e-6f);
            const float w5 = __logf(own.y + 1e-6f);
            const float w6 = __logf(own.z + 1e-6f);
            const float w7 = __logf(own.w + 1e-6f);
            const float h0 = __logf(hal.x + 1e-6f);  // garbage on non-halo lanes
            const float h1 = __logf(hal.y + 1e-6f);
            const float h2 = __logf(hal.z + 1e-6f);
            const float h3 = __logf(hal.w + 1e-6f);

            float win[12];
            win[4] = w4; win[5] = w5; win[6] = w6; win[7] = w7;
            win[0] = __shfl_up(w4, 1);
            win[1] = __shfl_up(w5, 1);
            win[2] = __shfl_up(w6, 1);
            win[3] = __shfl_up(w7, 1);
            win[8]  = __shfl_down(w4, 1);
            win[9]  = __shfl_down(w5, 1);
            win[10] = __shfl_down(w6, 1);
            win[11] = __shfl_down(w7, 1);
            if (is0) {
                if (ledge) { win[0] = w7; win[1] = w6; win[2] = w5; win[3] = w4; }
                else       { win[0] = h0; win[1] = h1; win[2] = h2; win[3] = h3; }
            }
            if (is63) {
                if (redge) { win[8] = w7; win[9] = w6; win[10] = w5; win[11] = w4; }
                else       { win[8] = h0; win[9] = h1; win[10] = h2; win[11] = h3; }
            }

            // W-blur -> ring slot u
#pragma unroll
            for (int i = 0; i < 4; ++i) {
                float o = 0.f;
#pragma unroll
                for (int t = 0; t < 9; ++t) o += tp.k[t] * win[i + t];
                ring[u][i] = o;
            }

            // H-blur + fp16 store once 9 rows live (output row r0+j-8)
            if (j >= 8) {
                float acc[4];
#pragma unroll
                for (int i = 0; i < 4; ++i) {
                    float o = 0.f;
#pragma unroll
                    for (int t = 0; t < 9; ++t)
                        o += tp.k[t] * ring[(u + 2 + t) % 10][i];  // row j-8+t
                    acc[i] = o;
                }
                const int ro = r0 + j - 8;
                __half2 pa, pb;
                pa.x = __float2half(acc[0]); pa.y = __float2half(acc[1]);
                pb.x = __float2half(acc[2]); pb.y = __float2half(acc[3]);
                ushort* dp = ws + (((ro * 8 + tile) * 96) + z) * 64 + inner;
                *(uint2*)dp = make_uint2(*(uint*)&pa, *(uint*)&pb);
            }
        }
    }
#undef FOLD
}

// ---------------------------------------------------------------------------
// Kernel 2: C-blur + N-blur + loss. TWO consecutive (h,w) points per thread:
//  - ws reads become uint (pair of halves) = 256B/wave-inst (was 128B)
//  - Ie/Ig reads become float2 = 512B/wave-inst (was 256B)
//  - half the vmem instructions per point
//  - C/N-blur ring kept in PACKED __half2 (both points in one reg):
//    v_pk_fma_f16 does both points per inst -> ring 54 regs, VALU halved.
//    Precision: smoothed-log ~ -1 +- 0.3, fp16 ulp ~5e-4 -> loss bias ~1e-4.
// grid (512), block (256); thread P handles points 2P, 2P+1.
// ---------------------------------------------------------------------------
__global__ __launch_bounds__(256)
void k_cn_loss(const ushort* __restrict__ ws, const float* __restrict__ Ie,
               const float* __restrict__ Ig, float* __restrict__ out,
               Taps tp, CMat cm)
{
    const int tid = threadIdx.x;
    const int P   = blockIdx.x * 256 + tid;      // pair index
    const int hw0 = P * 2;                       // first point (even)
    const ushort* wbase = ws + (hw0 >> 6) * (96 * 64) + (hw0 & 63);
    // E plane q: uint at wbase + q*64; G plane q: + (48+q)*64

    // packed constants
    __half2 k2[9], cw[3][3];
#pragma unroll
    for (int t = 0; t < 9; ++t) k2[t] = __float2half2_rn(tp.k[t]);
#pragma unroll
    for (int i = 0; i < 3; ++i)
#pragma unroll
        for (int j = 0; j < 3; ++j) cw[i][j] = __float2half2_rn(cm.w[i][j]);

    __half2 re[9][3];   // ring of C-blurred smoothed-log(E), slot = m % 9
    __half2 rg[9][3];

#define LOADRAW(m, uE, uG)                                                     \
    uE[0] = *(const uint*)(wbase + ((m) * 3 + 0) * 64);                        \
    uE[1] = *(const uint*)(wbase + ((m) * 3 + 1) * 64);                        \
    uE[2] = *(const uint*)(wbase + ((m) * 3 + 2) * 64);                        \
    uG[0] = *(const uint*)(wbase + (48 + (m) * 3 + 0) * 64);                   \
    uG[1] = *(const uint*)(wbase + (48 + (m) * 3 + 1) * 64);                   \
    uG[2] = *(const uint*)(wbase + (48 + (m) * 3 + 2) * 64);

#define CBLUR(u, dst)                                                          \
    {                                                                          \
        __half2 v0 = *(__half2*)&u[0];                                         \
        __half2 v1 = *(__half2*)&u[1];                                         \
        __half2 v2 = *(__half2*)&u[2];                                         \
        dst[0] = __hfma2(cw[0][0], v0, __hfma2(cw[0][1], v1, __hmul2(cw[0][2], v2))); \
        dst[1] = __hfma2(cw[1][0], v0, __hfma2(cw[1][1], v1, __hmul2(cw[1][2], v2))); \
        dst[2] = __hfma2(cw[2][0], v0, __hfma2(cw[2][1], v1, __hmul2(cw[2][2], v2))); \
    }

#pragma unroll
    for (int m = 0; m < 4; ++m) {
        uint uE[3], uG[3];
        LOADRAW(m, uE, uG);
        CBLUR(uE, re[m]); CBLUR(uG, rg[m]);
    }
    uint nuE[3], nuG[3];
    LOADRAW(4, nuE, nuG);
    float2 ieq[3], igq[3];
#pragma unroll
    for (int c = 0; c < 3; ++c) {
        ieq[c] = *(const float2*)(Ie + c * PLANE + hw0);
        igq[c] = *(const float2*)(Ig + c * PLANE + hw0);
    }

    float acc = 0.f;
#pragma unroll
    for (int n = 0; n < 16; ++n) {
        float2 nie[3], nig[3];
        if (n + 1 < 16) {
#pragma unroll
            for (int c = 0; c < 3; ++c) {
                nie[c] = *(const float2*)(Ie + ((n + 1) * 3 + c) * PLANE + hw0);
                nig[c] = *(const float2*)(Ig + ((n + 1) * 3 + c) * PLANE + hw0);
            }
        }
        const int mnew = n + 4;
        if (mnew < 16) {
            CBLUR(nuE, re[mnew % 9]); CBLUR(nuG, rg[mnew % 9]);
            if (mnew + 1 < 16) { LOADRAW(mnew + 1, nuE, nuG); }
        }
#pragma unroll
        for (int c = 0; c < 3; ++c) {
            __half2 se2 = __float2half2_rn(0.f), sg2 = se2;
#pragma unroll
            for (int t = 0; t < 9; ++t) {
                int m = n - 4 + t;
                m = (m < 0) ? (-1 - m) : ((m > 15) ? (31 - m) : m);  // compile-time
                se2 = __hfma2(k2[t], re[m % 9][c], se2);
                sg2 = __hfma2(k2[t], rg[m % 9][c], sg2);
            }
            const float se0 = __half2float(__low2half(se2));
            const float se1 = __half2float(__high2half(se2));
            const float sg0 = __half2float(__low2half(sg2));
            const float sg1 = __half2float(__high2half(sg2));

            // point 0
            {
                float ee = __expf(-se0), eg = __expf(-sg0);
                float Re = (ieq[c].x + 1e-6f) * ee;
                float Rg = (igq[c].x + 1e-6f) * eg;
                float Le = __builtin_amdgcn_rcpf(ee);
                float Lg = __builtin_amdgcn_rcpf(eg);
                float dr = Re - Rg, dl = Le - Lg;
                acc += dr * dr + dl * dl;
            }
            // point 1
            {
                float ee = __expf(-se1), eg = __expf(-sg1);
                float Re = (ieq[c].y + 1e-6f) * ee;
                float Rg = (igq[c].y + 1e-6f) * eg;
                float Le = __builtin_amdgcn_rcpf(ee);
                float Lg = __builtin_amdgcn_rcpf(eg);
                float dr = Re - Rg, dl = Le - Lg;
                acc += dr * dr + dl * dl;
            }
        }
        if (n + 1 < 16) {
#pragma unroll
            for (int c = 0; c < 3; ++c) { ieq[c] = nie[c]; igq[c] = nig[c]; }
        }
    }
#undef LOADRAW
#undef CBLUR

    __shared__ float red[256];
    red[tid] = acc;
    __syncthreads();
#pragma unroll
    for (int s = 128; s > 0; s >>= 1) {
        if (tid < s) red[tid] += red[tid + s];
        __syncthreads();
    }
    if (tid == 0) atomicAdd(out, red[0] * (1.0f / (float)NEL));
}

extern "C" void kernel_launch(void* const* d_in, const int* in_sizes, int n_in,
                              void* d_out, int out_size, void* d_ws, size_t ws_size,
                              hipStream_t stream) {
    const float* Ie = (const float*)d_in[0];
    const float* Ig = (const float*)d_in[1];

    // Gaussian taps: sigma=1, radius=int(4*1+0.5)=4, double-precision normalize
    Taps tp;
    {
        double kk[9], s = 0.0;
        for (int i = 0; i < 9; ++i) { double x = (double)(i - 4); kk[i] = exp(-0.5 * x * x); s += kk[i]; }
        for (int i = 0; i < 9; ++i) tp.k[i] = (float)(kk[i] / s);
    }

    // C-axis (size 3) 9-tap symmetric blur collapsed to a 3x3 matrix
    CMat cm;
    {
        for (int c = 0; c < 3; ++c) {
            cm.w[c][0] = cm.w[c][1] = cm.w[c][2] = 0.f;
            for (int t = 0; t < 9; ++t) {
                int m = c - 4 + t;
                int mm = ((m % 6) + 6) % 6;          // symmetric reflect, period 6
                if (mm > 2) mm = 5 - mm;
                cm.w[c][mm] += tp.k[t];
            }
        }
    }

    ushort* ws = (ushort*)d_ws;          // tiled fp16 blurred logs, 48 MB

    hipMemsetAsync(d_out, 0, sizeof(float), stream);  // zero the atomic target
    dim3 g1(32, 96);
    k_blur_hw<<<g1, 64, 0, stream>>>(Ie, Ig, ws, tp);
    k_cn_loss<<<512, 256, 0, stream>>>(ws, Ie, Ig, (float*)d_out, tp, cm);
}

// Round 10
// 165.079 us; speedup vs baseline: 1.1352x; 1.0483x over previous
//
#include <hip/hip_runtime.h>
#include <hip/hip_fp16.h>
#include <cmath>

// Problem constants: (N,C,H,W) = (16,3,512,512), fp32
#define PLANE (512*512)          // 262144
#define NPLANES 48               // N*C
#define NEL (48*PLANE)           // 12582912

struct Taps { float k[9]; };
struct CMat { float w[3][3]; };   // C-axis 9-tap blur collapsed to 3x3 matrix

// ws layout (all fp16, TILED): index(p, h, w) = ((h*8 + (w>>6))*96 + p)*64 + (w&63)
//   wsS[0 .. 2*NEL)   : HW-blurred log, planes 0..47 = image E, 48..95 = image G
//   wsI[0 .. 2*NEL)   : (I + 1e-6) center values, same plane order
// Total 4*NEL ushorts = 100.7 MB.  k_cn_loss touches ONLY ws (L2/L3-warm).

// ---------------------------------------------------------------------------
// Kernel 1: fused log + W-blur + H-blur + I-fp16 staging.
// One WAVE per (32-row strip x 256-col half). 4 cols/lane. W-halo: lanes
// 1..62 via shuffle; lanes 0/63 via one predicated float4 load (or register
// mirror at the image edge). Ring in PACKED half2; H-blur = 18 v_pk_fma_f16
// instead of 36 v_fma_f32. grid (32, 96), block 64.
// ---------------------------------------------------------------------------
__global__ __launch_bounds__(64)
void k_blur_hw(const float* __restrict__ inE, const float* __restrict__ inG,
               ushort* __restrict__ wsS, ushort* __restrict__ wsI, Taps tp)
{
    const int l    = threadIdx.x;
    const int w0   = (blockIdx.x & 1) * 256;     // W half
    const int r0   = (blockIdx.x >> 1) * 32;     // 16 rowgroups
    const int z    = blockIdx.y;                 // plane 0..95

    const float* src = (z < NPLANES) ? (inE + z * PLANE)
                                     : (inG + (z - NPLANES) * PLANE);

    const int  col   = w0 + 4 * l;               // first of this lane's 4 cols
    const bool is0   = (l == 0);
    const bool is63  = (l == 63);
    const bool ledge = (w0 == 0);
    const bool redge = (w0 + 256 == 512);
    const bool do_halo = (is0 && !ledge) || (is63 && !redge);
    const int  hoff  = is0 ? (w0 - 4) : (w0 + 256);  // halo float4 col
    const int  tile  = col >> 6;                 // w-tile 0..7
    const int  inner = col & 63;

    __half2 kh[9];
#pragma unroll
    for (int t = 0; t < 9; ++t) kh[t] = __float2half2_rn(tp.k[t]);

    __half2 ring[10][2];                         // W-blurred rows (4 cols packed)

#define FOLD(r) ((r) < 0 ? (-1 - (r)) : ((r) > 511 ? (1023 - (r)) : (r)))

    // preload rows j=0,1,2 (plane rows r0-4..r0-2)
    float4 pown[3], phal[3];
    phal[0] = phal[1] = phal[2] = make_float4(1.f, 1.f, 1.f, 1.f);
#pragma unroll
    for (int s = 0; s < 3; ++s) {
        const float* rp = src + FOLD(r0 - 4 + s) * 512;
        pown[s] = *(const float4*)(rp + col);
        if (do_halo) phal[s] = *(const float4*)(rp + hoff);
    }

    for (int jb = 0; jb < 40; jb += 10) {
#pragma unroll
        for (int u = 0; u < 10; ++u) {
            const int j = jb + u;                // input row 0..39 (plane r0-4+j)

            float4 own = pown[0], hal = phal[0];
            pown[0] = pown[1]; pown[1] = pown[2];
            phal[0] = phal[1]; phal[1] = phal[2];
            if (j + 3 < 40) {                    // load row j+3 (depth-3 pipe)
                const float* rp = src + FOLD(r0 - 1 + j) * 512;
                pown[2] = *(const float4*)(rp + col);
                if (do_halo) phal[2] = *(const float4*)(rp + hoff);
            }

            // stage (I + eps) as fp16 for the center rows (j=4..35 <-> r0..r0+31)
            if (j >= 4 && j < 36) {
                const int ri = r0 + j - 4;       // in [r0, r0+31], no fold
                __half2 i0 = __floats2half2_rn(own.x + 1e-6f, own.y + 1e-6f);
                __half2 i1 = __floats2half2_rn(own.z + 1e-6f, own.w + 1e-6f);
                ushort* dpI = wsI + (((ri * 8 + tile) * 96) + z) * 64 + inner;
                *(uint2*)dpI = make_uint2(*(uint*)&i0, *(uint*)&i1);
            }

            const float w4 = __logf(own.x + 1e-6f);
            const float w5 = __logf(own.y + 1e-6f);
            const float w6 = __logf(own.z + 1e-6f);
            const float w7 = __logf(own.w + 1e-6f);
            const float h0 = __logf(hal.x + 1e-6f);  // garbage on non-halo lanes
            const float h1 = __logf(hal.y + 1e-6f);
            const float h2 = __logf(hal.z + 1e-6f);
            const float h3 = __logf(hal.w + 1e-6f);

            float win[12];
            win[4] = w4; win[5] = w5; win[6] = w6; win[7] = w7;
            win[0] = __shfl_up(w4, 1);
            win[1] = __shfl_up(w5, 1);
            win[2] = __shfl_up(w6, 1);
            win[3] = __shfl_up(w7, 1);
            win[8]  = __shfl_down(w4, 1);
            win[9]  = __shfl_down(w5, 1);
            win[10] = __shfl_down(w6, 1);
            win[11] = __shfl_down(w7, 1);
            if (is0) {
                if (ledge) { win[0] = w7; win[1] = w6; win[2] = w5; win[3] = w4; }
                else       { win[0] = h0; win[1] = h1; win[2] = h2; win[3] = h3; }
            }
            if (is63) {
                if (redge) { win[8] = w7; win[9] = w6; win[10] = w5; win[11] = w4; }
                else       { win[8] = h0; win[9] = h1; win[10] = h2; win[11] = h3; }
            }

            // W-blur (fp32) -> packed half2 ring slot u
            {
                float o0 = 0.f, o1 = 0.f, o2 = 0.f, o3 = 0.f;
#pragma unroll
                for (int t = 0; t < 9; ++t) {
                    const float kt = tp.k[t];
                    o0 += kt * win[t];
                    o1 += kt * win[t + 1];
                    o2 += kt * win[t + 2];
                    o3 += kt * win[t + 3];
                }
                ring[u][0] = __floats2half2_rn(o0, o1);
                ring[u][1] = __floats2half2_rn(o2, o3);
            }

            // H-blur (packed fp16) + store once 9 rows live (output row r0+j-8)
            if (j >= 8) {
                __half2 a0 = __float2half2_rn(0.f), a1 = a0;
#pragma unroll
                for (int t = 0; t < 9; ++t) {
                    const int sl = (u + 2 + t) % 10;     // slot of row j-8+t
                    a0 = __hfma2(kh[t], ring[sl][0], a0);
                    a1 = __hfma2(kh[t], ring[sl][1], a1);
                }
                const int ro = r0 + j - 8;
                ushort* dpS = wsS + (((ro * 8 + tile) * 96) + z) * 64 + inner;
                *(uint2*)dpS = make_uint2(*(uint*)&a0, *(uint*)&a1);
            }
        }
    }
#undef FOLD
}

// ---------------------------------------------------------------------------
// Kernel 2: C-blur + N-blur + loss. TWO consecutive (h,w) points per thread;
// ALL loads from the warm fp16 tiled ws (S and I+eps) - no cold fp32 reads.
// Packed-half2 ring math (v_pk_fma_f16 does both points per inst).
// grid (512), block (256); thread P handles points 2P, 2P+1.
// ---------------------------------------------------------------------------
__global__ __launch_bounds__(256)
void k_cn_loss(const ushort* __restrict__ wsS, const ushort* __restrict__ wsI,
               float* __restrict__ out, Taps tp, CMat cm)
{
    const int tid = threadIdx.x;
    const int P   = blockIdx.x * 256 + tid;      // pair index
    const int hw0 = P * 2;                       // first point (even)
    const int off = (hw0 >> 6) * (96 * 64) + (hw0 & 63);
    const ushort* sbase = wsS + off;
    const ushort* ibase = wsI + off;
    // E plane q: uint at +q*64; G plane q: +(48+q)*64

    __half2 k2[9], cw[3][3];
#pragma unroll
    for (int t = 0; t < 9; ++t) k2[t] = __float2half2_rn(tp.k[t]);
#pragma unroll
    for (int i = 0; i < 3; ++i)
#pragma unroll
        for (int j = 0; j < 3; ++j) cw[i][j] = __float2half2_rn(cm.w[i][j]);

    __half2 re[9][3];   // ring of C-blurred smoothed-log(E), slot = m % 9
    __half2 rg[9][3];

#define LOADRAW(m, uE, uG)                                                     \
    uE[0] = *(const uint*)(sbase + ((m) * 3 + 0) * 64);                        \
    uE[1] = *(const uint*)(sbase + ((m) * 3 + 1) * 64);                        \
    uE[2] = *(const uint*)(sbase + ((m) * 3 + 2) * 64);                        \
    uG[0] = *(const uint*)(sbase + (48 + (m) * 3 + 0) * 64);                   \
    uG[1] = *(const uint*)(sbase + (48 + (m) * 3 + 1) * 64);                   \
    uG[2] = *(const uint*)(sbase + (48 + (m) * 3 + 2) * 64);

#define CBLUR(u, dst)                                                          \
    {                                                                          \
        __half2 v0 = *(__half2*)&u[0];                                         \
        __half2 v1 = *(__half2*)&u[1];                                         \
        __half2 v2 = *(__half2*)&u[2];                                         \
        dst[0] = __hfma2(cw[0][0], v0, __hfma2(cw[0][1], v1, __hmul2(cw[0][2], v2))); \
        dst[1] = __hfma2(cw[1][0], v0, __hfma2(cw[1][1], v1, __hmul2(cw[1][2], v2))); \
        dst[2] = __hfma2(cw[2][0], v0, __hfma2(cw[2][1], v1, __hmul2(cw[2][2], v2))); \
    }

#pragma unroll
    for (int m = 0; m < 4; ++m) {
        uint uE[3], uG[3];
        LOADRAW(m, uE, uG);
        CBLUR(uE, re[m]); CBLUR(uG, rg[m]);
    }
    uint nuE[3], nuG[3];
    LOADRAW(4, nuE, nuG);
    uint ieq[3], igq[3];                         // packed (I+eps) pairs
#pragma unroll
    for (int c = 0; c < 3; ++c) {
        ieq[c] = *(const uint*)(ibase + c * 64);
        igq[c] = *(const uint*)(ibase + (48 + c) * 64);
    }

    float acc = 0.f;
#pragma unroll
    for (int n = 0; n < 16; ++n) {
        uint nie[3], nig[3];
        if (n + 1 < 16) {
#pragma unroll
            for (int c = 0; c < 3; ++c) {
                nie[c] = *(const uint*)(ibase + (((n + 1) * 3 + c)) * 64);
                nig[c] = *(const uint*)(ibase + ((48 + (n + 1) * 3 + c)) * 64);
            }
        }
        const int mnew = n + 4;
        if (mnew < 16) {
            CBLUR(nuE, re[mnew % 9]); CBLUR(nuG, rg[mnew % 9]);
            if (mnew + 1 < 16) { LOADRAW(mnew + 1, nuE, nuG); }
        }
#pragma unroll
        for (int c = 0; c < 3; ++c) {
            __half2 se2 = __float2half2_rn(0.f), sg2 = se2;
#pragma unroll
            for (int t = 0; t < 9; ++t) {
                int m = n - 4 + t;
                m = (m < 0) ? (-1 - m) : ((m > 15) ? (31 - m) : m);  // compile-time
                se2 = __hfma2(k2[t], re[m % 9][c], se2);
                sg2 = __hfma2(k2[t], rg[m % 9][c], sg2);
            }
            const float2 sef = __half22float2(se2);
            const float2 sgf = __half22float2(sg2);
            const float2 ief = __half22float2(*(__half2*)&ieq[c]);
            const float2 igf = __half22float2(*(__half2*)&igq[c]);

            // point 0
            {
                float ee = __expf(-sef.x), eg = __expf(-sgf.x);
                float Re = ief.x * ee;
                float Rg = igf.x * eg;
                float Le = __builtin_amdgcn_rcpf(ee);
                float Lg = __builtin_amdgcn_rcpf(eg);
                float dr = Re - Rg, dl = Le - Lg;
                acc += dr * dr + dl * dl;
            }
            // point 1
            {
                float ee = __expf(-sef.y), eg = __expf(-sgf.y);
                float Re = ief.y * ee;
                float Rg = igf.y * eg;
                float Le = __builtin_amdgcn_rcpf(ee);
                float Lg = __builtin_amdgcn_rcpf(eg);
                float dr = Re - Rg, dl = Le - Lg;
                acc += dr * dr + dl * dl;
            }
        }
        if (n + 1 < 16) {
#pragma unroll
            for (int c = 0; c < 3; ++c) { ieq[c] = nie[c]; igq[c] = nig[c]; }
        }
    }
#undef LOADRAW
#undef CBLUR

    __shared__ float red[256];
    red[tid] = acc;
    __syncthreads();
#pragma unroll
    for (int s = 128; s > 0; s >>= 1) {
        if (tid < s) red[tid] += red[tid + s];
        __syncthreads();
    }
    if (tid == 0) atomicAdd(out, red[0] * (1.0f / (float)NEL));
}

extern "C" void kernel_launch(void* const* d_in, const int* in_sizes, int n_in,
                              void* d_out, int out_size, void* d_ws, size_t ws_size,
                              hipStream_t stream) {
    const float* Ie = (const float*)d_in[0];
    const float* Ig = (const float*)d_in[1];

    // Gaussian taps: sigma=1, radius=int(4*1+0.5)=4, double-precision normalize
    Taps tp;
    {
        double kk[9], s = 0.0;
        for (int i = 0; i < 9; ++i) { double x = (double)(i - 4); kk[i] = exp(-0.5 * x * x); s += kk[i]; }
        for (int i = 0; i < 9; ++i) tp.k[i] = (float)(kk[i] / s);
    }

    // C-axis (size 3) 9-tap symmetric blur collapsed to a 3x3 matrix
    CMat cm;
    {
        for (int c = 0; c < 3; ++c) {
            cm.w[c][0] = cm.w[c][1] = cm.w[c][2] = 0.f;
            for (int t = 0; t < 9; ++t) {
                int m = c - 4 + t;
                int mm = ((m % 6) + 6) % 6;          // symmetric reflect, period 6
                if (mm > 2) mm = 5 - mm;
                cm.w[c][mm] += tp.k[t];
            }
        }
    }

    ushort* wsS = (ushort*)d_ws;                 // fp16 blurred logs, 50.3 MB
    ushort* wsI = wsS + 2 * (size_t)NEL;         // fp16 (I+eps), 50.3 MB

    hipMemsetAsync(d_out, 0, sizeof(float), stream);  // zero the atomic target
    dim3 g1(32, 96);
    k_blur_hw<<<g1, 64, 0, stream>>>(Ie, Ig, wsS, wsI, tp);
    k_cn_loss<<<512, 256, 0, stream>>>(wsS, wsI, (float*)d_out, tp, cm);
}